// Round 7
// baseline (303.575 us; speedup 1.0000x reference)
//
#include <hip/hip_runtime.h>
#include <hip/hip_bf16.h>
#include <stdint.h>

#define BS 8
#define S  32
#define L  128
#define D  768
#define P  496

typedef float  f32x4  __attribute__((ext_vector_type(4)));
typedef __bf16 bf16x8 __attribute__((ext_vector_type(8)));
typedef __bf16 bf16x4 __attribute__((ext_vector_type(4)));

// ---------------- K1: zero float4s (cls output) ----------------
__global__ void k_zero(float4* __restrict__ p, int n) {
  int i = blockIdx.x * blockDim.x + threadIdx.x;
  if (i < n) p[i] = make_float4(0.f, 0.f, 0.f, 0.f);
}

// ---------------- K2: fused prep: W1T + zero scores + x->bf16 ----------------
// blocks [0,2304): w1t transpose+cvt; [2304,2336): zero scores;
// [2336,26912): x cvt (24576 blocks * 256 thr = 6291456 float4s exactly)
#define PREP_CVT_BASE 2336
#define PREP_NBLK (PREP_CVT_BASE + 24576)
__global__ void k_prep(const float* __restrict__ w1, __bf16* __restrict__ w1t,
                       float4* __restrict__ scores4,
                       const float4* __restrict__ x, bf16x4* __restrict__ xb) {
  int blk = blockIdx.x, tid = threadIdx.x;
  if (blk < 2304) {
    int idx = blk * 256 + tid;                // idx = h*D + d (writes coalesced)
    int h = idx / D, d = idx - h * D;
    w1t[idx] = (__bf16)w1[d * D + h];
  } else if (blk < PREP_CVT_BASE) {
    int i = (blk - 2304) * 256 + tid;         // 8192 float4s
    if (i < (BS * S * L) / 4) scores4[i] = make_float4(0.f, 0.f, 0.f, 0.f);
  } else {
    int i = (blk - PREP_CVT_BASE) * 256 + tid; // 6291456 float4s exactly
    float4 v = x[i];
    bf16x4 h = { (__bf16)v.x, (__bf16)v.y, (__bf16)v.z, (__bf16)v.w };
    xb[i] = h;
  }
}

// ---------------- K3: scatter x_cls rows into cls output ----------------
__global__ void k_scatter(const float4* __restrict__ xcls, const int* __restrict__ pairs,
                          const int* __restrict__ pnum, float4* __restrict__ outc) {
  int p = blockIdx.x, b = blockIdx.y;
  if (p >= pnum[b]) return;
  int i = pairs[(b * P + p) * 2 + 0];
  int j = pairs[(b * P + p) * 2 + 1];
  const float4* src = xcls + (size_t)(b * P + p) * (D / 4);
  float4*       dst = outc + (size_t)((b * S + i) * S + j) * (D / 4);
  dst[threadIdx.x] = src[threadIdx.x];
}

// ---------------- K4: scores GEMM ----------------
// 128x128 tile, BK=32 (64B rows -> bank-even ds_read_b128, no swizzle needed),
// 4 waves (2x2), dbuf LDS 32KB total -> 5 WGs/CU. global_load_lds width 16.
// Epilogue: tanh + w2-dot -> shfl reduce -> atomicAdd into zeroed scores.
#define GEMM_LDS 32768   // 2 bufs x (A 8KB + B 8KB)

__global__ __launch_bounds__(256, 5) void k_gemm_scores(
    const __bf16* __restrict__ xb, const __bf16* __restrict__ w1t,
    const float* __restrict__ b1, const float* __restrict__ w2,
    float* __restrict__ scores)
{
  extern __shared__ char smem[];

  // XCD-aware swizzle: nwg = 1536, 1536 % 8 == 0, chunk = 192
  int bid = blockIdx.x;
  int swz = (bid & 7) * 192 + (bid >> 3);
  int bm = swz / 6, bn = swz - 6 * bm;        // 256 M-tiles x 6 N-tiles

  const int tid  = threadIdx.x;
  const int lane = tid & 63, wv = tid >> 6;   // 4 waves
  const int wm = wv >> 1, wn = wv & 1;        // 2x2 -> 64x64 per wave
  const int lo = lane & 15, kg = lane >> 4;

  // staging source addresses (per-lane). o = inst*4096 + tid*16 within 8KB tile.
  // tile row r = o/64 (64B per row at BK=32), chunk c = (o/16)%4. Linear, no swizzle.
  const char* Ag[2];
  const char* Bg[2];
  int ldsOff[2];
  #pragma unroll
  for (int inst = 0; inst < 2; ++inst) {
    int o = inst * 4096 + tid * 16;
    int r = o >> 6;
    int c = (o >> 4) & 3;
    Ag[inst] = (const char*)xb  + (size_t)(bm * 128 + r) * (D * 2) + c * 16;
    Bg[inst] = (const char*)w1t + (size_t)(bn * 128 + r) * (D * 2) + c * 16;
    ldsOff[inst] = inst * 4096 + wv * 1024;   // wave-uniform dest (HW appends lane*16)
  }

  auto STAGE = [&](int buf, int t) {
    char* base = smem + buf * 16384;
    const size_t koff = (size_t)t * 64;
    #pragma unroll
    for (int inst = 0; inst < 2; ++inst) {
      __builtin_amdgcn_global_load_lds(
          (const __attribute__((address_space(1))) void*)(Ag[inst] + koff),
          (__attribute__((address_space(3))) void*)(base + ldsOff[inst]), 16, 0, 0);
      __builtin_amdgcn_global_load_lds(
          (const __attribute__((address_space(1))) void*)(Bg[inst] + koff),
          (__attribute__((address_space(3))) void*)(base + 8192 + ldsOff[inst]), 16, 0, 0);
    }
  };

  f32x4 acc[4][4];
  #pragma unroll
  for (int mf = 0; mf < 4; ++mf)
    #pragma unroll
    for (int nf = 0; nf < 4; ++nf)
      acc[mf][nf] = (f32x4){0.f, 0.f, 0.f, 0.f};

  STAGE(0, 0);
  __syncthreads();

  for (int t = 0; t < 24; ++t) {
    const int cur = t & 1;
    if (t < 23) STAGE(cur ^ 1, t + 1);

    const char* As = smem + cur * 16384;
    const char* Bs = As + 8192;
    bf16x8 a[4], b[4];
    #pragma unroll
    for (int mf = 0; mf < 4; ++mf)
      a[mf] = *(const bf16x8*)(As + (wm * 64 + mf * 16 + lo) * 64 + kg * 16);
    #pragma unroll
    for (int nf = 0; nf < 4; ++nf)
      b[nf] = *(const bf16x8*)(Bs + (wn * 64 + nf * 16 + lo) * 64 + kg * 16);
    #pragma unroll
    for (int mf = 0; mf < 4; ++mf)
      #pragma unroll
      for (int nf = 0; nf < 4; ++nf)
        acc[mf][nf] = __builtin_amdgcn_mfma_f32_16x16x32_bf16(a[mf], b[nf], acc[mf][nf], 0, 0, 0);

    __syncthreads();
  }

  // epilogue: tanh + w2 dot over this block's 128 cols, reduce, atomicAdd
  float part[4][4];
  #pragma unroll
  for (int mf = 0; mf < 4; ++mf)
    #pragma unroll
    for (int r = 0; r < 4; ++r) part[mf][r] = 0.f;

  #pragma unroll
  for (int nf = 0; nf < 4; ++nf) {
    int n = bn * 128 + wn * 64 + nf * 16 + lo;
    float b1v = b1[n], w2v = w2[n];
    #pragma unroll
    for (int mf = 0; mf < 4; ++mf)
      #pragma unroll
      for (int r = 0; r < 4; ++r) {
        float z = acc[mf][nf][r] + b1v;
        float e = __expf(2.f * z);
        part[mf][r] += w2v * (1.f - 2.f / (e + 1.f));
      }
  }
  #pragma unroll
  for (int mf = 0; mf < 4; ++mf)
    #pragma unroll
    for (int r = 0; r < 4; ++r) {
      float v = part[mf][r];
      v += __shfl_xor(v, 1);
      v += __shfl_xor(v, 2);
      v += __shfl_xor(v, 4);
      v += __shfl_xor(v, 8);
      part[mf][r] = v;
    }
  if (lo == 0) {
    int rowb = bm * 128 + wm * 64;
    #pragma unroll
    for (int mf = 0; mf < 4; ++mf)
      #pragma unroll
      for (int r = 0; r < 4; ++r)
        atomicAdd(&scores[rowb + mf * 16 + kg * 4 + r], part[mf][r]);
  }
}

// ---------------- K5: fused masked softmax + final_sent ----------------
// One block per (b,s): 384 threads. Threads 0..127 compute softmax into LDS,
// then all 384 threads each produce 2 output d's (bf16x2 loads, coalesced).
__global__ __launch_bounds__(384) void k_probs_final(
    const float* __restrict__ scores, const float* __restrict__ mask,
    const __bf16* __restrict__ xb, float* __restrict__ out)
{
  int bs = blockIdx.x, t = threadIdx.x;
  __shared__ float sc[L];
  __shared__ float p[L];
  if (t < L) sc[t] = scores[bs * L + t] + (1.f - mask[bs * L + t]) * -10000.f;
  __syncthreads();
  if (t < L) {
    float mx = -1e30f;
    #pragma unroll 8
    for (int l = 0; l < L; ++l) mx = fmaxf(mx, sc[l]);
    float sum = 0.f;
    #pragma unroll 8
    for (int l = 0; l < L; ++l) sum += __expf(sc[l] - mx);
    p[t] = __expf(sc[t] - mx) / sum;
  }
  __syncthreads();

  const uint32_t* xp = (const uint32_t*)(xb + (size_t)bs * L * D) + t;  // 2 bf16 per thread
  float a0 = 0.f, a1 = 0.f;
  #pragma unroll 4
  for (int l = 0; l < L; ++l) {
    uint32_t u = xp[(size_t)l * (D / 2)];
    float pl = p[l];
    a0 += pl * __uint_as_float(u << 16);
    a1 += pl * __uint_as_float(u & 0xffff0000u);
  }
  ((float2*)(out + (size_t)bs * D))[t] = make_float2(a0, a1);
}

// ---------------- launch ----------------
extern "C" void kernel_launch(void* const* d_in, const int* in_sizes, int n_in,
                              void* d_out, int out_size, void* d_ws, size_t ws_size,
                              hipStream_t stream) {
  const float* x    = (const float*)d_in[0];
  const float* xcls = (const float*)d_in[1];
  const float* mask = (const float*)d_in[2];
  const float* w1   = (const float*)d_in[3];
  const float* b1   = (const float*)d_in[4];
  const float* w2   = (const float*)d_in[5];
  // d_in[6] = b2: softmax is shift-invariant, b2 cancels exactly.
  const int* pairs  = (const int*)d_in[7];
  const int* pnum   = (const int*)d_in[8];

  float* out_final = (float*)d_out;                      // (8,32,768)
  float* out_cls   = (float*)d_out + (size_t)BS * S * D; // (8,32,32,768)

  // workspace layout
  __bf16* xb    = (__bf16*)d_ws;                                  // 50.3 MB
  __bf16* w1t   = (__bf16*)((char*)d_ws + (size_t)BS * S * L * D * 2);
  float* scores = (float*)((char*)w1t + (size_t)D * D * 2);

  {
    int n = (BS * S * S * D) / 4;
    k_zero<<<(n + 255) / 256, 256, 0, stream>>>((float4*)out_cls, n);
  }
  k_prep<<<PREP_NBLK, 256, 0, stream>>>(w1, w1t, (float4*)scores, (const float4*)x, (bf16x4*)xb);
  k_scatter<<<dim3(P, BS), D / 4, 0, stream>>>((const float4*)xcls, pairs, pnum, (float4*)out_cls);

  k_gemm_scores<<<(32768 / 128) * (D / 128), 256, GEMM_LDS, stream>>>(xb, w1t, b1, w2, scores);

  k_probs_final<<<BS * S, 384, 0, stream>>>(scores, mask, xb, out_final);
}

// Round 8
// 277.797 us; speedup vs baseline: 1.0928x; 1.0928x over previous
//
#include <hip/hip_runtime.h>
#include <hip/hip_bf16.h>
#include <stdint.h>

#define BS 8
#define S  32
#define L  128
#define D  768
#define P  496

typedef float  f32x4  __attribute__((ext_vector_type(4)));
typedef __bf16 bf16x8 __attribute__((ext_vector_type(8)));
typedef __bf16 bf16x4 __attribute__((ext_vector_type(4)));

// ---------------- K1: zero float4s (cls output) ----------------
__global__ void k_zero(float4* __restrict__ p, int n) {
  int i = blockIdx.x * blockDim.x + threadIdx.x;
  if (i < n) p[i] = make_float4(0.f, 0.f, 0.f, 0.f);
}

// ---------------- K2: fused prep: W1T (LDS transpose) + zero scores + x->bf16 ----------------
// blocks [0,144): w1t 64x64 tile transpose+cvt (coalesced both sides);
// [144,176): zero scores; [176,176+24576): x cvt (6291456 float4s exactly)
#define PREP_ZERO_BASE 144
#define PREP_CVT_BASE  176
#define PREP_NBLK (PREP_CVT_BASE + 24576)
__global__ void k_prep(const float* __restrict__ w1, __bf16* __restrict__ w1t,
                       float4* __restrict__ scores4,
                       const float4* __restrict__ x, bf16x4* __restrict__ xb) {
  __shared__ float tile[64][65];              // +1 pad: conflict-free transposed read
  int blk = blockIdx.x, t = threadIdx.x;
  if (blk < PREP_ZERO_BASE) {
    int dblk = blk / 12, hblk = blk - 12 * dblk;
    #pragma unroll 4
    for (int i = 0; i < 16; ++i) {
      int d_local = i * 4 + (t >> 6);
      tile[d_local][t & 63] = w1[(size_t)(dblk * 64 + d_local) * D + hblk * 64 + (t & 63)];
    }
    __syncthreads();
    #pragma unroll 4
    for (int i = 0; i < 16; ++i) {
      int h_local = i * 4 + (t >> 6);
      w1t[(size_t)(hblk * 64 + h_local) * D + dblk * 64 + (t & 63)] =
          (__bf16)tile[t & 63][h_local];
    }
  } else if (blk < PREP_CVT_BASE) {
    int i = (blk - PREP_ZERO_BASE) * 256 + t; // 8192 float4s
    if (i < (BS * S * L) / 4) scores4[i] = make_float4(0.f, 0.f, 0.f, 0.f);
  } else {
    int i = (blk - PREP_CVT_BASE) * 256 + t;  // 6291456 float4s exactly
    float4 v = x[i];
    bf16x4 h = { (__bf16)v.x, (__bf16)v.y, (__bf16)v.z, (__bf16)v.w };
    xb[i] = h;
  }
}

// ---------------- K3: scatter x_cls rows into cls output ----------------
__global__ void k_scatter(const float4* __restrict__ xcls, const int* __restrict__ pairs,
                          const int* __restrict__ pnum, float4* __restrict__ outc) {
  int p = blockIdx.x, b = blockIdx.y;
  if (p >= pnum[b]) return;
  int i = pairs[(b * P + p) * 2 + 0];
  int j = pairs[(b * P + p) * 2 + 1];
  const float4* src = xcls + (size_t)(b * P + p) * (D / 4);
  float4*       dst = outc + (size_t)((b * S + i) * S + j) * (D / 4);
  dst[threadIdx.x] = src[threadIdx.x];
}

// ---------------- K4: scores GEMM ----------------
// 128x128 tile, BK=32 (64B rows). Swizzle: chunk ^= (row>>1)&3 — spreads each
// 16-lane kg-group over all 8 b128 bank-slots (2-way = free; was 8-way).
// Applied on global SOURCE (LDS dest linear, global_load_lds constraint) and
// on ds_read. 32KB LDS -> 5 WG/CU. Epilogue: tanh + w2-dot -> atomicAdd.
#define GEMM_LDS 32768   // 2 bufs x (A 8KB + B 8KB)

__global__ __launch_bounds__(256, 5) void k_gemm_scores(
    const __bf16* __restrict__ xb, const __bf16* __restrict__ w1t,
    const float* __restrict__ b1, const float* __restrict__ w2,
    float* __restrict__ scores)
{
  extern __shared__ char smem[];

  // XCD-aware swizzle: nwg = 1536, 1536 % 8 == 0, chunk = 192
  int bid = blockIdx.x;
  int swz = (bid & 7) * 192 + (bid >> 3);
  int bm = swz / 6, bn = swz - 6 * bm;        // 256 M-tiles x 6 N-tiles

  const int tid  = threadIdx.x;
  const int lane = tid & 63, wv = tid >> 6;   // 4 waves
  const int wm = wv >> 1, wn = wv & 1;        // 2x2 -> 64x64 per wave
  const int lo = lane & 15, kg = lane >> 4;

  // staging source (per-lane, inverse-swizzled): o = inst*4096 + tid*16
  const char* Ag[2];
  const char* Bg[2];
  int ldsOff[2];
  #pragma unroll
  for (int inst = 0; inst < 2; ++inst) {
    int o  = inst * 4096 + tid * 16;
    int r  = o >> 6;                          // tile row 0..127
    int c  = (o >> 4) & 3;                    // 16B chunk in 64B row
    int sc = c ^ ((r >> 1) & 3);              // inverse swizzle on source
    Ag[inst] = (const char*)xb  + (size_t)(bm * 128 + r) * (D * 2) + sc * 16;
    Bg[inst] = (const char*)w1t + (size_t)(bn * 128 + r) * (D * 2) + sc * 16;
    ldsOff[inst] = inst * 4096 + wv * 1024;   // wave-uniform dest (HW appends lane*16)
  }

  auto STAGE = [&](int buf, int t) {
    char* base = smem + buf * 16384;
    const size_t koff = (size_t)t * 64;
    #pragma unroll
    for (int inst = 0; inst < 2; ++inst) {
      __builtin_amdgcn_global_load_lds(
          (const __attribute__((address_space(1))) void*)(Ag[inst] + koff),
          (__attribute__((address_space(3))) void*)(base + ldsOff[inst]), 16, 0, 0);
      __builtin_amdgcn_global_load_lds(
          (const __attribute__((address_space(1))) void*)(Bg[inst] + koff),
          (__attribute__((address_space(3))) void*)(base + 8192 + ldsOff[inst]), 16, 0, 0);
    }
  };

  f32x4 acc[4][4];
  #pragma unroll
  for (int mf = 0; mf < 4; ++mf)
    #pragma unroll
    for (int nf = 0; nf < 4; ++nf)
      acc[mf][nf] = (f32x4){0.f, 0.f, 0.f, 0.f};

  STAGE(0, 0);
  __syncthreads();

  const int sw = (lo >> 1) & 3;               // read-side swizzle (row>>1)&3

  for (int t = 0; t < 24; ++t) {
    const int cur = t & 1;
    if (t < 23) STAGE(cur ^ 1, t + 1);

    const char* As = smem + cur * 16384;
    const char* Bs = As + 8192;
    bf16x8 a[4], b[4];
    #pragma unroll
    for (int mf = 0; mf < 4; ++mf)
      a[mf] = *(const bf16x8*)(As + (wm * 64 + mf * 16 + lo) * 64 + ((kg ^ sw) * 16));
    #pragma unroll
    for (int nf = 0; nf < 4; ++nf)
      b[nf] = *(const bf16x8*)(Bs + (wn * 64 + nf * 16 + lo) * 64 + ((kg ^ sw) * 16));
    #pragma unroll
    for (int mf = 0; mf < 4; ++mf)
      #pragma unroll
      for (int nf = 0; nf < 4; ++nf)
        acc[mf][nf] = __builtin_amdgcn_mfma_f32_16x16x32_bf16(a[mf], b[nf], acc[mf][nf], 0, 0, 0);

    __syncthreads();
  }

  // epilogue: tanh + w2 dot over this block's 128 cols, reduce, atomicAdd
  float part[4][4];
  #pragma unroll
  for (int mf = 0; mf < 4; ++mf)
    #pragma unroll
    for (int r = 0; r < 4; ++r) part[mf][r] = 0.f;

  #pragma unroll
  for (int nf = 0; nf < 4; ++nf) {
    int n = bn * 128 + wn * 64 + nf * 16 + lo;
    float b1v = b1[n], w2v = w2[n];
    #pragma unroll
    for (int mf = 0; mf < 4; ++mf)
      #pragma unroll
      for (int r = 0; r < 4; ++r) {
        float z = acc[mf][nf][r] + b1v;
        float e = __expf(2.f * z);
        part[mf][r] += w2v * (1.f - 2.f / (e + 1.f));
      }
  }
  #pragma unroll
  for (int mf = 0; mf < 4; ++mf)
    #pragma unroll
    for (int r = 0; r < 4; ++r) {
      float v = part[mf][r];
      v += __shfl_xor(v, 1);
      v += __shfl_xor(v, 2);
      v += __shfl_xor(v, 4);
      v += __shfl_xor(v, 8);
      part[mf][r] = v;
    }
  if (lo == 0) {
    int rowb = bm * 128 + wm * 64;
    #pragma unroll
    for (int mf = 0; mf < 4; ++mf)
      #pragma unroll
      for (int r = 0; r < 4; ++r)
        atomicAdd(&scores[rowb + mf * 16 + kg * 4 + r], part[mf][r]);
  }
}

// ---------------- K5: fused masked softmax + final_sent ----------------
__global__ __launch_bounds__(384) void k_probs_final(
    const float* __restrict__ scores, const float* __restrict__ mask,
    const __bf16* __restrict__ xb, float* __restrict__ out)
{
  int bs = blockIdx.x, t = threadIdx.x;
  __shared__ float sc[L];
  __shared__ float p[L];
  if (t < L) sc[t] = scores[bs * L + t] + (1.f - mask[bs * L + t]) * -10000.f;
  __syncthreads();
  if (t < L) {
    float mx = -1e30f;
    #pragma unroll 8
    for (int l = 0; l < L; ++l) mx = fmaxf(mx, sc[l]);
    float sum = 0.f;
    #pragma unroll 8
    for (int l = 0; l < L; ++l) sum += __expf(sc[l] - mx);
    p[t] = __expf(sc[t] - mx) / sum;
  }
  __syncthreads();

  const uint32_t* xp = (const uint32_t*)(xb + (size_t)bs * L * D) + t;  // 2 bf16 per thread
  float a0 = 0.f, a1 = 0.f;
  #pragma unroll 4
  for (int l = 0; l < L; ++l) {
    uint32_t u = xp[(size_t)l * (D / 2)];
    float pl = p[l];
    a0 += pl * __uint_as_float(u << 16);
    a1 += pl * __uint_as_float(u & 0xffff0000u);
  }
  ((float2*)(out + (size_t)bs * D))[t] = make_float2(a0, a1);
}

// ---------------- launch ----------------
extern "C" void kernel_launch(void* const* d_in, const int* in_sizes, int n_in,
                              void* d_out, int out_size, void* d_ws, size_t ws_size,
                              hipStream_t stream) {
  const float* x    = (const float*)d_in[0];
  const float* xcls = (const float*)d_in[1];
  const float* mask = (const float*)d_in[2];
  const float* w1   = (const float*)d_in[3];
  const float* b1   = (const float*)d_in[4];
  const float* w2   = (const float*)d_in[5];
  // d_in[6] = b2: softmax is shift-invariant, b2 cancels exactly.
  const int* pairs  = (const int*)d_in[7];
  const int* pnum   = (const int*)d_in[8];

  float* out_final = (float*)d_out;                      // (8,32,768)
  float* out_cls   = (float*)d_out + (size_t)BS * S * D; // (8,32,32,768)

  // workspace layout
  __bf16* xb    = (__bf16*)d_ws;                                  // 48 MB
  __bf16* w1t   = (__bf16*)((char*)d_ws + (size_t)BS * S * L * D * 2);
  float* scores = (float*)((char*)w1t + (size_t)D * D * 2);

  {
    int n = (BS * S * S * D) / 4;
    k_zero<<<(n + 255) / 256, 256, 0, stream>>>((float4*)out_cls, n);
  }
  k_prep<<<PREP_NBLK, 256, 0, stream>>>(w1, w1t, (float4*)scores, (const float4*)x, (bf16x4*)xb);
  k_scatter<<<dim3(P, BS), D / 4, 0, stream>>>((const float4*)xcls, pairs, pnum, (float4*)out_cls);

  k_gemm_scores<<<(32768 / 128) * (D / 128), 256, GEMM_LDS, stream>>>(xb, w1t, b1, w2, scores);

  k_probs_final<<<BS * S, 384, 0, stream>>>(scores, mask, xb, out_final);
}

// Round 9
// 273.806 us; speedup vs baseline: 1.1087x; 1.0146x over previous
//
#include <hip/hip_runtime.h>
#include <hip/hip_bf16.h>
#include <stdint.h>

#define BS 8
#define S  32
#define L  128
#define D  768
#define P  496

typedef float  f32x4  __attribute__((ext_vector_type(4)));
typedef __bf16 bf16x8 __attribute__((ext_vector_type(8)));
typedef __bf16 bf16x4 __attribute__((ext_vector_type(4)));

// ---------------- K1: zero float4s (cls output) ----------------
__global__ void k_zero(float4* __restrict__ p, int n) {
  int i = blockIdx.x * blockDim.x + threadIdx.x;
  if (i < n) p[i] = make_float4(0.f, 0.f, 0.f, 0.f);
}

// ---------------- K2: fused prep: W1T (LDS transpose) + zero scores + x->bf16 ----------------
#define PREP_ZERO_BASE 144
#define PREP_CVT_BASE  176
#define PREP_NBLK (PREP_CVT_BASE + 24576)
__global__ void k_prep(const float* __restrict__ w1, __bf16* __restrict__ w1t,
                       float4* __restrict__ scores4,
                       const float4* __restrict__ x, bf16x4* __restrict__ xb) {
  __shared__ float tile[64][65];              // +1 pad: conflict-free transposed read
  int blk = blockIdx.x, t = threadIdx.x;
  if (blk < PREP_ZERO_BASE) {
    int dblk = blk / 12, hblk = blk - 12 * dblk;
    #pragma unroll 4
    for (int i = 0; i < 16; ++i) {
      int d_local = i * 4 + (t >> 6);
      tile[d_local][t & 63] = w1[(size_t)(dblk * 64 + d_local) * D + hblk * 64 + (t & 63)];
    }
    __syncthreads();
    #pragma unroll 4
    for (int i = 0; i < 16; ++i) {
      int h_local = i * 4 + (t >> 6);
      w1t[(size_t)(hblk * 64 + h_local) * D + dblk * 64 + (t & 63)] =
          (__bf16)tile[t & 63][h_local];
    }
  } else if (blk < PREP_CVT_BASE) {
    int i = (blk - PREP_ZERO_BASE) * 256 + t; // 8192 float4s
    if (i < (BS * S * L) / 4) scores4[i] = make_float4(0.f, 0.f, 0.f, 0.f);
  } else {
    int i = (blk - PREP_CVT_BASE) * 256 + t;  // 6291456 float4s exactly
    float4 v = x[i];
    bf16x4 h = { (__bf16)v.x, (__bf16)v.y, (__bf16)v.z, (__bf16)v.w };
    xb[i] = h;
  }
}

// ---------------- K3: scatter x_cls rows into cls output ----------------
__global__ void k_scatter(const float4* __restrict__ xcls, const int* __restrict__ pairs,
                          const int* __restrict__ pnum, float4* __restrict__ outc) {
  int p = blockIdx.x, b = blockIdx.y;
  if (p >= pnum[b]) return;
  int i = pairs[(b * P + p) * 2 + 0];
  int j = pairs[(b * P + p) * 2 + 1];
  const float4* src = xcls + (size_t)(b * P + p) * (D / 4);
  float4*       dst = outc + (size_t)((b * S + i) * S + j) * (D / 4);
  dst[threadIdx.x] = src[threadIdx.x];
}

// ---------------- K4: scores GEMM ----------------
// 128x128 tile, BK=32, swizzle chunk^=(row>>1)&3 (0 bank conflicts, round 8).
// NEW: 3-buffer depth-2 prefetch with counted vmcnt (T4): never drain vmcnt
// to 0 in the main loop — stages t+1,t+2 (4 vm ops each) stay in flight, so
// wait vmcnt(8) before consuming tile t. Raw s_barrier (no implicit drain).
// LDS 48KB -> 3 WG/CU; grid 1536 = 6/CU -> balanced (3,3) cohorts.
#define GEMM_LDS 49152   // 3 bufs x (A 8KB + B 8KB)

__global__ __launch_bounds__(256) void k_gemm_scores(
    const __bf16* __restrict__ xb, const __bf16* __restrict__ w1t,
    const float* __restrict__ b1, const float* __restrict__ w2,
    float* __restrict__ scores)
{
  extern __shared__ char smem[];

  // XCD-aware swizzle: nwg = 1536, 1536 % 8 == 0, chunk = 192
  int bid = blockIdx.x;
  int swz = (bid & 7) * 192 + (bid >> 3);
  int bm = swz / 6, bn = swz - 6 * bm;        // 256 M-tiles x 6 N-tiles

  const int tid  = threadIdx.x;
  const int lane = tid & 63, wv = tid >> 6;   // 4 waves
  const int wm = wv >> 1, wn = wv & 1;        // 2x2 -> 64x64 per wave
  const int lo = lane & 15, kg = lane >> 4;

  // staging source (per-lane, inverse-swizzled): o = inst*4096 + tid*16
  const char* Ag[2];
  const char* Bg[2];
  int ldsOff[2];
  #pragma unroll
  for (int inst = 0; inst < 2; ++inst) {
    int o  = inst * 4096 + tid * 16;
    int r  = o >> 6;                          // tile row 0..127
    int c  = (o >> 4) & 3;                    // 16B chunk in 64B row
    int sc = c ^ ((r >> 1) & 3);              // inverse swizzle on source
    Ag[inst] = (const char*)xb  + (size_t)(bm * 128 + r) * (D * 2) + sc * 16;
    Bg[inst] = (const char*)w1t + (size_t)(bn * 128 + r) * (D * 2) + sc * 16;
    ldsOff[inst] = inst * 4096 + wv * 1024;   // wave-uniform dest (HW appends lane*16)
  }

  // 4 global_load_lds (vm ops) per wave per STAGE
  auto STAGE = [&](int buf, int t) {
    char* base = smem + buf * 16384;
    const size_t koff = (size_t)t * 64;
    #pragma unroll
    for (int inst = 0; inst < 2; ++inst) {
      __builtin_amdgcn_global_load_lds(
          (const __attribute__((address_space(1))) void*)(Ag[inst] + koff),
          (__attribute__((address_space(3))) void*)(base + ldsOff[inst]), 16, 0, 0);
      __builtin_amdgcn_global_load_lds(
          (const __attribute__((address_space(1))) void*)(Bg[inst] + koff),
          (__attribute__((address_space(3))) void*)(base + 8192 + ldsOff[inst]), 16, 0, 0);
    }
  };

  f32x4 acc[4][4];
  #pragma unroll
  for (int mf = 0; mf < 4; ++mf)
    #pragma unroll
    for (int nf = 0; nf < 4; ++nf)
      acc[mf][nf] = (f32x4){0.f, 0.f, 0.f, 0.f};

  const int sw = (lo >> 1) & 3;               // read-side swizzle (row>>1)&3

  // one K-step body: consume buffer (tt%3); caller already staged ahead.
  auto BODY = [&](int tt) {
    const char* As = smem + (tt % 3) * 16384;
    const char* Bs = As + 8192;
    bf16x8 a[4], b[4];
    #pragma unroll
    for (int mf = 0; mf < 4; ++mf)
      a[mf] = *(const bf16x8*)(As + (wm * 64 + mf * 16 + lo) * 64 + ((kg ^ sw) * 16));
    #pragma unroll
    for (int nf = 0; nf < 4; ++nf)
      b[nf] = *(const bf16x8*)(Bs + (wn * 64 + nf * 16 + lo) * 64 + ((kg ^ sw) * 16));
    #pragma unroll
    for (int mf = 0; mf < 4; ++mf)
      #pragma unroll
      for (int nf = 0; nf < 4; ++nf)
        acc[mf][nf] = __builtin_amdgcn_mfma_f32_16x16x32_bf16(a[mf], b[nf], acc[mf][nf], 0, 0, 0);
    // read-done barrier: this wave's MFMAs forced its lgkm drain, so after
    // this barrier every wave has finished reading buf (tt%3) -> safe to
    // overwrite next iteration.
    __builtin_amdgcn_s_barrier();
    __builtin_amdgcn_sched_barrier(0);
  };

  // prologue: stages 0 and 1 in flight (8 vm ops)
  STAGE(0, 0);
  STAGE(1, 1);

  // main loop: t = 0..21, stage t+2, wait for t (<=8 outstanding), consume t
  for (int t = 0; t < 22; ++t) {
    STAGE((t + 2) % 3, t + 2);
    asm volatile("s_waitcnt vmcnt(8)" ::: "memory");
    __builtin_amdgcn_s_barrier();
    __builtin_amdgcn_sched_barrier(0);
    BODY(t);
  }
  // t = 22: stage 23 still in flight (4 ops)
  asm volatile("s_waitcnt vmcnt(4)" ::: "memory");
  __builtin_amdgcn_s_barrier();
  __builtin_amdgcn_sched_barrier(0);
  BODY(22);
  // t = 23: nothing in flight
  asm volatile("s_waitcnt vmcnt(0)" ::: "memory");
  __builtin_amdgcn_s_barrier();
  __builtin_amdgcn_sched_barrier(0);
  BODY(23);

  // epilogue: tanh + w2 dot over this block's 128 cols, reduce, atomicAdd
  float part[4][4];
  #pragma unroll
  for (int mf = 0; mf < 4; ++mf)
    #pragma unroll
    for (int r = 0; r < 4; ++r) part[mf][r] = 0.f;

  #pragma unroll
  for (int nf = 0; nf < 4; ++nf) {
    int n = bn * 128 + wn * 64 + nf * 16 + lo;
    float b1v = b1[n], w2v = w2[n];
    #pragma unroll
    for (int mf = 0; mf < 4; ++mf)
      #pragma unroll
      for (int r = 0; r < 4; ++r) {
        float z = acc[mf][nf][r] + b1v;
        float e = __expf(2.f * z);
        part[mf][r] += w2v * (1.f - 2.f / (e + 1.f));
      }
  }
  #pragma unroll
  for (int mf = 0; mf < 4; ++mf)
    #pragma unroll
    for (int r = 0; r < 4; ++r) {
      float v = part[mf][r];
      v += __shfl_xor(v, 1);
      v += __shfl_xor(v, 2);
      v += __shfl_xor(v, 4);
      v += __shfl_xor(v, 8);
      part[mf][r] = v;
    }
  if (lo == 0) {
    int rowb = bm * 128 + wm * 64;
    #pragma unroll
    for (int mf = 0; mf < 4; ++mf)
      #pragma unroll
      for (int r = 0; r < 4; ++r)
        atomicAdd(&scores[rowb + mf * 16 + kg * 4 + r], part[mf][r]);
  }
}

// ---------------- K5: fused masked softmax + final_sent ----------------
__global__ __launch_bounds__(384) void k_probs_final(
    const float* __restrict__ scores, const float* __restrict__ mask,
    const __bf16* __restrict__ xb, float* __restrict__ out)
{
  int bs = blockIdx.x, t = threadIdx.x;
  __shared__ float sc[L];
  __shared__ float p[L];
  if (t < L) sc[t] = scores[bs * L + t] + (1.f - mask[bs * L + t]) * -10000.f;
  __syncthreads();
  if (t < L) {
    float mx = -1e30f;
    #pragma unroll 8
    for (int l = 0; l < L; ++l) mx = fmaxf(mx, sc[l]);
    float sum = 0.f;
    #pragma unroll 8
    for (int l = 0; l < L; ++l) sum += __expf(sc[l] - mx);
    p[t] = __expf(sc[t] - mx) / sum;
  }
  __syncthreads();

  const uint32_t* xp = (const uint32_t*)(xb + (size_t)bs * L * D) + t;  // 2 bf16 per thread
  float a0 = 0.f, a1 = 0.f;
  #pragma unroll 4
  for (int l = 0; l < L; ++l) {
    uint32_t u = xp[(size_t)l * (D / 2)];
    float pl = p[l];
    a0 += pl * __uint_as_float(u << 16);
    a1 += pl * __uint_as_float(u & 0xffff0000u);
  }
  ((float2*)(out + (size_t)bs * D))[t] = make_float2(a0, a1);
}

// ---------------- launch ----------------
extern "C" void kernel_launch(void* const* d_in, const int* in_sizes, int n_in,
                              void* d_out, int out_size, void* d_ws, size_t ws_size,
                              hipStream_t stream) {
  const float* x    = (const float*)d_in[0];
  const float* xcls = (const float*)d_in[1];
  const float* mask = (const float*)d_in[2];
  const float* w1   = (const float*)d_in[3];
  const float* b1   = (const float*)d_in[4];
  const float* w2   = (const float*)d_in[5];
  // d_in[6] = b2: softmax is shift-invariant, b2 cancels exactly.
  const int* pairs  = (const int*)d_in[7];
  const int* pnum   = (const int*)d_in[8];

  float* out_final = (float*)d_out;                      // (8,32,768)
  float* out_cls   = (float*)d_out + (size_t)BS * S * D; // (8,32,32,768)

  // workspace layout
  __bf16* xb    = (__bf16*)d_ws;                                  // 48 MB
  __bf16* w1t   = (__bf16*)((char*)d_ws + (size_t)BS * S * L * D * 2);
  float* scores = (float*)((char*)w1t + (size_t)D * D * 2);

  {
    int n = (BS * S * S * D) / 4;
    k_zero<<<(n + 255) / 256, 256, 0, stream>>>((float4*)out_cls, n);
  }
  k_prep<<<PREP_NBLK, 256, 0, stream>>>(w1, w1t, (float4*)scores, (const float4*)x, (bf16x4*)xb);
  k_scatter<<<dim3(P, BS), D / 4, 0, stream>>>((const float4*)xcls, pairs, pnum, (float4*)out_cls);

  hipFuncSetAttribute((const void*)k_gemm_scores, hipFuncAttributeMaxDynamicSharedMemorySize, GEMM_LDS);
  k_gemm_scores<<<(32768 / 128) * (D / 128), 256, GEMM_LDS, stream>>>(xb, w1t, b1, w2, scores);

  k_probs_final<<<BS * S, 384, 0, stream>>>(scores, mask, xb, out_final);
}